// Round 15
// baseline (1034.931 us; speedup 1.0000x reference)
//
#include <hip/hip_runtime.h>
#include <hip/hip_bf16.h>

#define NODES_C 64
#define HEADS 4
#define HEAD_D 16

// f32 -> bf16 with round-to-nearest-even (deterministic, branch-free)
__device__ __forceinline__ unsigned short f32_to_bf16(float f) {
    unsigned int x = __float_as_uint(f);
    unsigned int r = x + 0x7fffu + ((x >> 16) & 1u);
    return (unsigned short)(r >> 16);
}
// bf16 (raw ushort) -> f32
#define BF16_DEC(h) __uint_as_float(((unsigned int)(h)) << 16)
// packed {lo,hi} bf16 pair in a uint -> two floats
#define PAIR_DECODE(u, lo, hi)                              \
    lo = __uint_as_float((u) << 16);                        \
    hi = __uint_as_float((u) & 0xffff0000u);

// ---------------------------------------------------------------------------
// CSR build
// ---------------------------------------------------------------------------
__global__ void count_k(const int* __restrict__ dst, int E, int* __restrict__ deg) {
    int e = blockIdx.x * blockDim.x + threadIdx.x;
    if (e < E) atomicAdd(&deg[dst[e]], 1);
}

__global__ __launch_bounds__(1024) void scan_chunk(const int* __restrict__ deg,
                                                   int* __restrict__ excl,
                                                   int* __restrict__ chunkSums, int N) {
    __shared__ int buf[1024];
    int i = blockIdx.x * 1024 + threadIdx.x;
    int v = (i < N) ? deg[i] : 0;
    buf[threadIdx.x] = v;
    __syncthreads();
    for (int off = 1; off < 1024; off <<= 1) {
        int t = (threadIdx.x >= off) ? buf[threadIdx.x - off] : 0;
        __syncthreads();
        buf[threadIdx.x] += t;
        __syncthreads();
    }
    if (i < N) excl[i] = buf[threadIdx.x] - v;   // exclusive within chunk
    if (threadIdx.x == 1023) chunkSums[blockIdx.x] = buf[1023];
}

__global__ __launch_bounds__(128) void scan_sums(int* __restrict__ chunkSums, int nChunks) {
    __shared__ int buf[128];
    int v = (threadIdx.x < nChunks) ? chunkSums[threadIdx.x] : 0;
    buf[threadIdx.x] = v;
    __syncthreads();
    for (int off = 1; off < 128; off <<= 1) {
        int t = (threadIdx.x >= off) ? buf[threadIdx.x - off] : 0;
        __syncthreads();
        buf[threadIdx.x] += t;
        __syncthreads();
    }
    if (threadIdx.x < nChunks) chunkSums[threadIdx.x] = buf[threadIdx.x] - v;  // exclusive
}

__global__ void scan_add(int* __restrict__ excl, const int* __restrict__ chunkSums,
                         int N, int E) {
    int i = blockIdx.x * blockDim.x + threadIdx.x;
    if (i < N) excl[i] += chunkSums[i >> 10];
    if (i == 0) excl[N] = E;
}

__global__ void fill_k(const int* __restrict__ dst, int E,
                       const int* __restrict__ row_start, int* __restrict__ cursor,
                       int* __restrict__ csr) {
    int e = blockIdx.x * blockDim.x + threadIdx.x;
    if (e < E) {
        int d = dst[e];
        int pos = atomicAdd(&cursor[d], 1);
        csr[row_start[d] + pos] = e;
    }
}

// ---------------------------------------------------------------------------
// DETERMINISM (verified R9): sort each CSR row by edge id so the atomic
// fill order doesn't leak into f32 summation order. One thread per row.
// ---------------------------------------------------------------------------
__global__ void sort_rows_k(const int* __restrict__ row_start, int* __restrict__ csr,
                            int N) {
    int i = blockIdx.x * blockDim.x + threadIdx.x;
    if (i >= N) return;
    int beg = row_start[i], end = row_start[i + 1];
    for (int p = beg + 1; p < end; ++p) {
        int key = csr[p];
        int j = p - 1;
        while (j >= beg && csr[j] > key) { csr[j + 1] = csr[j]; --j; }
        csr[j + 1] = key;
    }
}

// ---------------------------------------------------------------------------
// One-time edge-data permutation into CSR order, bf16 output (R14).
// ---------------------------------------------------------------------------
__global__ void gather_edges(const int* __restrict__ csr, const int* __restrict__ srcA,
                             const float4* __restrict__ ea4,
                             int* __restrict__ csr_src,
                             unsigned short* __restrict__ csr_eah, int E) {
    int t = blockIdx.x * blockDim.x + threadIdx.x;
    int p = t >> 2, q = t & 3;
    if (p < E) {
        int e = csr[p];
        if (q == 0) csr_src[p] = srcA[e];
        float4 v = ea4[(size_t)e * 4 + q];
        ushort4 h;
        h.x = f32_to_bf16(v.x);  h.y = f32_to_bf16(v.y);
        h.z = f32_to_bf16(v.z);  h.w = f32_to_bf16(v.w);
        *(ushort4*)(csr_eah + (size_t)p * 16 + q * 4) = h;
    }
}

// ---------------------------------------------------------------------------
// Fused node projections, 2-column register tile (R13).
// K/V stored as BF16 PAIRS: KVh[n*128+2c]={K}, [..+1]={V} (verified R11).
// ---------------------------------------------------------------------------
#define GB 16
__global__ __launch_bounds__(128) void gemm_qkvs(
    const float* __restrict__ Hin,
    const float* __restrict__ Wq, const float* __restrict__ bq,
    const float* __restrict__ Wk, const float* __restrict__ bk,
    const float* __restrict__ Wv, const float* __restrict__ bv,
    const float* __restrict__ Ws, const float* __restrict__ bs,
    float* __restrict__ Q, unsigned short* __restrict__ KVh,
    float* __restrict__ Ssk, int N)
{
    int g = threadIdx.x >> 6;          // 0: Q+K, 1: V+S
    int c = threadIdx.x & 63;
    const float* W1 = (g == 0) ? Wq : Wv;
    const float* b1 = (g == 0) ? bq : bv;
    const float* W2 = (g == 0) ? Wk : Ws;
    const float* b2 = (g == 0) ? bk : bs;

    float w1[64], w2[64];
#pragma unroll
    for (int t = 0; t < 64; ++t) {
        w1[t] = W1[t * 64 + c];
        w2[t] = W2[t * 64 + c];
    }
    float bias1 = b1[c], bias2 = b2[c];

    __shared__ __align__(16) float hrow[GB][64];

    for (int base = blockIdx.x * GB; base < N; base += gridDim.x * GB) {
        int nn = min(GB, N - base);
        __syncthreads();
        for (int idx = threadIdx.x; idx < nn * 64; idx += 128)
            hrow[idx >> 6][idx & 63] = Hin[base * 64 + idx];
        __syncthreads();
        for (int r = 0; r < nn; ++r) {
            const float4* h4 = (const float4*)hrow[r];
            float acc1 = bias1, acc2 = bias2;
#pragma unroll
            for (int t4 = 0; t4 < 16; ++t4) {
                float4 hv = h4[t4];
                acc1 += hv.x * w1[4 * t4 + 0];
                acc1 += hv.y * w1[4 * t4 + 1];
                acc1 += hv.z * w1[4 * t4 + 2];
                acc1 += hv.w * w1[4 * t4 + 3];
                acc2 += hv.x * w2[4 * t4 + 0];
                acc2 += hv.y * w2[4 * t4 + 1];
                acc2 += hv.z * w2[4 * t4 + 2];
                acc2 += hv.w * w2[4 * t4 + 3];
            }
            size_t row = (size_t)(base + r);
            if (g == 0) {                                  // wave-uniform
                Q[row * 64 + c] = acc1;                    // Q  (f32)
                KVh[row * 128 + 2 * c] = f32_to_bf16(acc2);// K  (bf16)
            } else {
                KVh[row * 128 + 2 * c + 1] = f32_to_bf16(acc1); // V (bf16)
                Ssk[row * 64 + c] = acc2;                  // S  (f32)
            }
        }
    }
}

// ---------------------------------------------------------------------------
// Edge-softmax attention (R15): HALF-WAVE EDGE PAIRING.
// Lane L: half=L>>5, l5=L&31, channel pair c0=2*l5,c1=c0+1, head h=l5>>3
// (8 lanes per head), edge-attr dims t0=2*(l5&7), t1=t0+1.
// The two wave halves process two DIFFERENT edges of the same node at once,
// each maintaining its own online-softmax state; one deterministic
// cross-half merge per node. Per edge: VMEM insts halved (uint2 KV,
// packed-uint ea), 8-lane reduce (3 shfl vs 4, shared by 2 edges), exp /2.
// ---------------------------------------------------------------------------
__global__ __launch_bounds__(256) void attn_pre(
    const float* __restrict__ Q, const unsigned int* __restrict__ KVu,
    const float* __restrict__ Ssk,
    const int* __restrict__ row_start, const int* __restrict__ csr_src,
    const unsigned short* __restrict__ csr_eah,   // [E][16] bf16, CSR order
    const float* __restrict__ We, const float* __restrict__ be,
    float* __restrict__ Hout, int N, int doRelu)
{
    __shared__ float weS[16 * 68];          // padded rows
    for (int idx = threadIdx.x; idx < 1024; idx += 256)
        weS[(idx >> 6) * 68 + (idx & 63)] = We[idx];
    __syncthreads();

    int lane = threadIdx.x & 63;
    int half = lane >> 5;
    int l5   = lane & 31;
    int c0   = 2 * l5;                      // channel pair c0, c0+1
    int h    = l5 >> 3;                     // head (8 lanes per head)
    int t0   = 2 * (l5 & 7);                // edge-attr dim pair t0, t0+1

    // epilogue fold weights: We[2u+r][c0], We[2u+r][c1] for u=0..7, r=0,1
    float wA0[8], wA1[8], wB0[8], wB1[8];
#pragma unroll
    for (int u = 0; u < 8; ++u) {
        wA0[u] = weS[(2 * u) * 68 + c0];
        wA1[u] = weS[(2 * u + 1) * 68 + c0];
        wB0[u] = weS[(2 * u) * 68 + c0 + 1];
        wB1[u] = weS[(2 * u + 1) * 68 + c0 + 1];
    }
    float be0 = be[c0], be1 = be[c0 + 1];

    int gwave  = (blockIdx.x * blockDim.x + threadIdx.x) >> 6;
    int nwaves = (gridDim.x * blockDim.x) >> 6;

    const float4* w0r = (const float4*)(weS + t0 * 68 + 16 * h);
    const float4* w1r = (const float4*)(weS + (t0 + 1) * 68 + 16 * h);
    float4 wr00 = w0r[0], wr01 = w0r[1], wr02 = w0r[2], wr03 = w0r[3];
    float4 wr10 = w1r[0], wr11 = w1r[1], wr12 = w1r[2], wr13 = w1r[3];

    for (int i = gwave; i < N; i += nwaves) {
        // ---- per-node prologue ----
        float2 qp = *(const float2*)(Q + (size_t)i * 64 + c0);
        float q0 = qp.x, q1 = qp.y;

        const float4* qh4 = (const float4*)(Q + (size_t)i * 64 + 16 * h);
        float4 qv0 = qh4[0], qv1 = qh4[1], qv2 = qh4[2], qv3 = qh4[3];
        // G_t = sum_{c in head} q_c We[t][c], for this lane's t0 and t1
        float G0 = qv0.x * wr00.x + qv0.y * wr00.y + qv0.z * wr00.z + qv0.w * wr00.w
                 + qv1.x * wr01.x + qv1.y * wr01.y + qv1.z * wr01.z + qv1.w * wr01.w
                 + qv2.x * wr02.x + qv2.y * wr02.y + qv2.z * wr02.z + qv2.w * wr02.w
                 + qv3.x * wr03.x + qv3.y * wr03.y + qv3.z * wr03.z + qv3.w * wr03.w;
        float G1 = qv0.x * wr10.x + qv0.y * wr10.y + qv0.z * wr10.z + qv0.w * wr10.w
                 + qv1.x * wr11.x + qv1.y * wr11.y + qv1.z * wr11.z + qv1.w * wr11.w
                 + qv2.x * wr12.x + qv2.y * wr12.y + qv2.z * wr12.z + qv2.w * wr12.w
                 + qv3.x * wr13.x + qv3.y * wr13.y + qv3.z * wr13.z + qv3.w * wr13.w;

        float rb = q0 * be0 + q1 * be1;
        rb += __shfl_xor(rb, 4, 8);
        rb += __shfl_xor(rb, 2, 8);
        rb += __shfl_xor(rb, 1, 8);
        float qbase = rb * 0.25f;

        int beg = row_start[i], end = row_start[i + 1];
        float m = -INFINITY, s = 0.f, acc0 = 0.f, acc1 = 0.f, z0 = 0.f, z1 = 0.f;

        int p = beg;
        // ---- 8-edge main loop: 4 slots, each half handles one edge/slot ----
        for (; p + 7 < end; p += 8) {
            int e0 = p + half, e1 = p + 2 + half, e2 = p + 4 + half, e3 = p + 6 + half;
            int j0 = csr_src[e0], j1 = csr_src[e1];
            int j2 = csr_src[e2], j3 = csr_src[e3];
            uint2 kv0 = *(const uint2*)(KVu + (size_t)j0 * 64 + c0);
            uint2 kv1 = *(const uint2*)(KVu + (size_t)j1 * 64 + c0);
            uint2 kv2 = *(const uint2*)(KVu + (size_t)j2 * 64 + c0);
            uint2 kv3 = *(const uint2*)(KVu + (size_t)j3 * 64 + c0);
            unsigned int ua0 = *(const unsigned int*)(csr_eah + (size_t)e0 * 16 + t0);
            unsigned int ua1 = *(const unsigned int*)(csr_eah + (size_t)e1 * 16 + t0);
            unsigned int ua2 = *(const unsigned int*)(csr_eah + (size_t)e2 * 16 + t0);
            unsigned int ua3 = *(const unsigned int*)(csr_eah + (size_t)e3 * 16 + t0);

            float k00, v00, k01, v01;  PAIR_DECODE(kv0.x, k00, v00)  PAIR_DECODE(kv0.y, k01, v01)
            float k10, v10, k11, v11;  PAIR_DECODE(kv1.x, k10, v10)  PAIR_DECODE(kv1.y, k11, v11)
            float k20, v20, k21, v21;  PAIR_DECODE(kv2.x, k20, v20)  PAIR_DECODE(kv2.y, k21, v21)
            float k30, v30, k31, v31;  PAIR_DECODE(kv3.x, k30, v30)  PAIR_DECODE(kv3.y, k31, v31)
            float a00, a01;  PAIR_DECODE(ua0, a00, a01)
            float a10, a11;  PAIR_DECODE(ua1, a10, a11)
            float a20, a21;  PAIR_DECODE(ua2, a20, a21)
            float a30, a31;  PAIR_DECODE(ua3, a30, a31)

            float p0 = q0 * k00 + q1 * k01 + a00 * G0 + a01 * G1;
            float p1 = q0 * k10 + q1 * k11 + a10 * G0 + a11 * G1;
            float p2 = q0 * k20 + q1 * k21 + a20 * G0 + a21 * G1;
            float p3 = q0 * k30 + q1 * k31 + a30 * G0 + a31 * G1;
#pragma unroll
            for (int off = 4; off >= 1; off >>= 1) {
                p0 += __shfl_xor(p0, off, 8);
                p1 += __shfl_xor(p1, off, 8);
                p2 += __shfl_xor(p2, off, 8);
                p3 += __shfl_xor(p3, off, 8);
            }
            float l0 = p0 * 0.25f + qbase;
            float l1 = p1 * 0.25f + qbase;
            float l2 = p2 * 0.25f + qbase;
            float l3 = p3 * 0.25f + qbase;

            float nm = fmaxf(fmaxf(fmaxf(l0, l1), fmaxf(l2, l3)), m);
            float sc = __expf(m - nm);
            float w0 = __expf(l0 - nm), w1 = __expf(l1 - nm);
            float w2 = __expf(l2 - nm), w3 = __expf(l3 - nm);
            s    = s * sc + ((w0 + w1) + (w2 + w3));
            acc0 = acc0 * sc + ((w0 * v00 + w1 * v10) + (w2 * v20 + w3 * v30));
            acc1 = acc1 * sc + ((w0 * v01 + w1 * v11) + (w2 * v21 + w3 * v31));
            z0   = z0 * sc + ((w0 * a00 + w1 * a10) + (w2 * a20 + w3 * a30));
            z1   = z1 * sc + ((w0 * a01 + w1 * a11) + (w2 * a21 + w3 * a31));
            m = nm;
        }
        // ---- pair tail (one slot = 2 edges) ----
        for (; p + 1 < end; p += 2) {
            int e = p + half;
            int j = csr_src[e];
            uint2 kv = *(const uint2*)(KVu + (size_t)j * 64 + c0);
            unsigned int ua = *(const unsigned int*)(csr_eah + (size_t)e * 16 + t0);
            float k0, v0, k1, v1;  PAIR_DECODE(kv.x, k0, v0)  PAIR_DECODE(kv.y, k1, v1)
            float a0, a1;  PAIR_DECODE(ua, a0, a1)
            float pt = q0 * k0 + q1 * k1 + a0 * G0 + a1 * G1;
#pragma unroll
            for (int off = 4; off >= 1; off >>= 1) pt += __shfl_xor(pt, off, 8);
            float l = pt * 0.25f + qbase;
            float nm = fmaxf(m, l);
            float sc = __expf(m - nm);
            float w  = __expf(l - nm);
            s    = s * sc + w;
            acc0 = acc0 * sc + w * v0;
            acc1 = acc1 * sc + w * v1;
            z0   = z0 * sc + w * a0;
            z1   = z1 * sc + w * a1;
            m = nm;
        }
        // ---- odd final edge: computed by both halves, applied by half 0 ----
        if (p < end) {
            int j = csr_src[p];
            uint2 kv = *(const uint2*)(KVu + (size_t)j * 64 + c0);
            unsigned int ua = *(const unsigned int*)(csr_eah + (size_t)p * 16 + t0);
            float k0, v0, k1, v1;  PAIR_DECODE(kv.x, k0, v0)  PAIR_DECODE(kv.y, k1, v1)
            float a0, a1;  PAIR_DECODE(ua, a0, a1)
            float pt = q0 * k0 + q1 * k1 + a0 * G0 + a1 * G1;
#pragma unroll
            for (int off = 4; off >= 1; off >>= 1) pt += __shfl_xor(pt, off, 8);
            float l = pt * 0.25f + qbase;
            if (half == 0) {
                float nm = fmaxf(m, l);
                float sc = __expf(m - nm);
                float w  = __expf(l - nm);
                s    = s * sc + w;
                acc0 = acc0 * sc + w * v0;
                acc1 = acc1 * sc + w * v1;
                z0   = z0 * sc + w * a0;
                z1   = z1 * sc + w * a1;
                m = nm;
            }
        }

        // ---- deterministic cross-half merge ----
        float mo  = __shfl_xor(m, 32);
        float so  = __shfl_xor(s, 32);
        float ao0 = __shfl_xor(acc0, 32);
        float ao1 = __shfl_xor(acc1, 32);
        float zo0 = __shfl_xor(z0, 32);
        float zo1 = __shfl_xor(z1, 32);
        float nmm = fmaxf(m, mo);
        float cs = __expf(m - nmm), co = __expf(mo - nmm);
        s    = s * cs + so * co;
        acc0 = acc0 * cs + ao0 * co;
        acc1 = acc1 * cs + ao1 * co;
        z0   = z0 * cs + zo0 * co;
        z1   = z1 * cs + zo1 * co;

        // ---- epilogue: fold edge-projection back in ----
        float2 sk = *(const float2*)(Ssk + (size_t)i * 64 + c0);
        float o0, o1;
        if (s > 0.f) {
            float t0v = acc0, t1v = acc1;
#pragma unroll
            for (int u = 0; u < 8; ++u) {
                float zz0 = __shfl(z0, u, 8);
                float zz1 = __shfl(z1, u, 8);
                t0v += wA0[u] * zz0 + wA1[u] * zz1;
                t1v += wB0[u] * zz0 + wB1[u] * zz1;
            }
            o0 = t0v / s + be0 + sk.x;
            o1 = t1v / s + be1 + sk.y;
        } else {
            o0 = sk.x;
            o1 = sk.y;
        }
        if (doRelu) { o0 = fmaxf(o0, 0.f); o1 = fmaxf(o1, 0.f); }
        if (half == 0)
            *(float2*)(Hout + (size_t)i * 64 + c0) = make_float2(o0, o1);
    }
}

// ---------------------------------------------------------------------------
// Fallback attention (direct algorithm) — only if ws can't hold csr_eah.
// ---------------------------------------------------------------------------
#define KV_DECODE(u, kf, vf)                                \
    kf = __uint_as_float((u) << 16);                        \
    vf = __uint_as_float((u) & 0xffff0000u);

__global__ __launch_bounds__(256) void attn_k(
    const float* __restrict__ Q, const unsigned int* __restrict__ KVu,
    const float* __restrict__ Ssk,
    const int* __restrict__ row_start, const int* __restrict__ csr,
    const int* __restrict__ srcA, const float* __restrict__ edge_attr,
    const float* __restrict__ We, const float* __restrict__ be,
    float* __restrict__ Hout, int N, int doRelu)
{
    int lane = threadIdx.x & 63;
    float wcol[16];
#pragma unroll
    for (int t = 0; t < 16; ++t) wcol[t] = We[t * 64 + lane];
    float beL = be[lane];

    int gwave  = (blockIdx.x * blockDim.x + threadIdx.x) >> 6;
    int nwaves = (gridDim.x * blockDim.x) >> 6;

    for (int i = gwave; i < N; i += nwaves) {
        float q = Q[(size_t)i * 64 + lane];
        int beg = row_start[i], end = row_start[i + 1];
        float m = -INFINITY, s = 0.f, acc = 0.f;
        for (int p = beg; p < end; ++p) {
            int e = csr[p];
            int j = srcA[e];
            const float4* ap = (const float4*)(edge_attr + (size_t)e * 16);
            float4 a0 = ap[0], a1 = ap[1], a2 = ap[2], a3 = ap[3];
            unsigned int u = KVu[(size_t)j * 64 + lane];
            float kf, vf;
            KV_DECODE(u, kf, vf)
            float ea = beL;
            ea += a0.x * wcol[0]  + a0.y * wcol[1]  + a0.z * wcol[2]  + a0.w * wcol[3];
            ea += a1.x * wcol[4]  + a1.y * wcol[5]  + a1.z * wcol[6]  + a1.w * wcol[7];
            ea += a2.x * wcol[8]  + a2.y * wcol[9]  + a2.z * wcol[10] + a2.w * wcol[11];
            ea += a3.x * wcol[12] + a3.y * wcol[13] + a3.z * wcol[14] + a3.w * wcol[15];
            float kv = kf + ea, vv = vf + ea;
            float part = q * kv;
#pragma unroll
            for (int off = 8; off >= 1; off >>= 1) part += __shfl_xor(part, off, 16);
            float logit = part * 0.25f;
            float nm = fmaxf(m, logit);
            float sc = __expf(m - nm);
            float w  = __expf(logit - nm);
            s = s * sc + w;  acc = acc * sc + w * vv;  m = nm;
        }
        float agg = (s > 0.f) ? acc / s : 0.f;
        float o = agg + Ssk[(size_t)i * 64 + lane];
        if (doRelu) o = fmaxf(o, 0.f);
        Hout[(size_t)i * 64 + lane] = o;
    }
}

// ---------------------------------------------------------------------------
// Deterministic global mean pool (verified R9): one block per graph,
// binary-searched boundaries, fixed-order LDS combine, no atomics.
// ---------------------------------------------------------------------------
__device__ __forceinline__ int lbound(const int* __restrict__ a, int n, int key) {
    int lo = 0, hi = n;
    while (lo < hi) { int mid = (lo + hi) >> 1; if (a[mid] < key) lo = mid + 1; else hi = mid; }
    return lo;
}

__global__ __launch_bounds__(256) void pool_mean_k(
    const float* __restrict__ H, const int* __restrict__ batch,
    float* __restrict__ pooled, int N)
{
    int g = blockIdx.x;
    int lo = lbound(batch, N, g);
    int hi = lbound(batch, N, g + 1);
    int lane = threadIdx.x & 63;
    int w = threadIdx.x >> 6;

    float acc = 0.f;
    for (int i = lo + w; i < hi; i += 4)
        acc += H[(size_t)i * 64 + lane];

    __shared__ float part[4][64];
    part[w][lane] = acc;
    __syncthreads();
    if (w == 0) {
        float s = ((part[0][lane] + part[1][lane]) + part[2][lane]) + part[3][lane];
        float cnt = (float)(hi - lo);
        pooled[g * 64 + lane] = s / fmaxf(cnt, 1.0f);
    }
}

__global__ __launch_bounds__(64) void mlp_k(
    const float* __restrict__ pooled,      // means
    const float* __restrict__ lin1_w, const float* __restrict__ lin1_b,
    const float* __restrict__ lin2_w, const float* __restrict__ lin2_b,
    float* __restrict__ out)
{
    int g = blockIdx.x;
    int c = threadIdx.x;
    float acc = lin1_b[c];
#pragma unroll
    for (int t = 0; t < 64; ++t) acc += pooled[g * 64 + t] * lin1_w[t * 64 + c];
    float r = fmaxf(acc, 0.f) * lin2_w[c];
#pragma unroll
    for (int off = 32; off >= 1; off >>= 1) r += __shfl_xor(r, off, 64);
    if (c == 0) out[g] = r + lin2_b[0];
}

// ---------------------------------------------------------------------------
extern "C" void kernel_launch(void* const* d_in, const int* in_sizes, int n_in,
                              void* d_out, int out_size, void* d_ws, size_t ws_size,
                              hipStream_t stream) {
    const float* x        = (const float*)d_in[0];
    const int*   eidx     = (const int*)  d_in[1];
    const float* eattr    = (const float*)d_in[2];
    const int*   batch    = (const int*)  d_in[3];
    const float* Wq       = (const float*)d_in[4];
    const float* bq       = (const float*)d_in[5];
    const float* Wk       = (const float*)d_in[6];
    const float* bk       = (const float*)d_in[7];
    const float* Wv       = (const float*)d_in[8];
    const float* bv       = (const float*)d_in[9];
    const float* We       = (const float*)d_in[10];
    const float* be       = (const float*)d_in[11];
    const float* Wskip    = (const float*)d_in[12];
    const float* bskip    = (const float*)d_in[13];
    const float* lin1_w   = (const float*)d_in[14];
    const float* lin1_b   = (const float*)d_in[15];
    const float* lin2_w   = (const float*)d_in[16];
    const float* lin2_b   = (const float*)d_in[17];

    int N = in_sizes[0] / 64;
    int E = in_sizes[1] / 2;
    const int* src = eidx;
    const int* dst = eidx + E;

    // workspace layout
    char* w = (char*)d_ws;
    auto alloc = [&](size_t bytes) {
        char* p = w;
        w += (bytes + 255) & ~(size_t)255;
        return p;
    };
    float* Q   = (float*)alloc((size_t)N * 64 * 4);
    unsigned short* KVh = (unsigned short*)alloc((size_t)N * 128 * 2);  // bf16 {K,V} pairs
    float* S   = (float*)alloc((size_t)N * 64 * 4);
    float* H   = (float*)alloc((size_t)N * 64 * 4);
    // deg and cursor adjacent -> single memset covers both
    int* deg       = (int*)alloc((size_t)N * 4);
    int* cursor    = (int*)alloc((size_t)N * 4);
    int* row_start = (int*)alloc((size_t)(N + 1) * 4);
    int* csr       = (int*)alloc((size_t)E * 4);
    int* chunkSums = (int*)alloc(128 * 4);
    float* pooled  = (float*)alloc(128 * 64 * 4);
    // fast-path extras (checked against ws_size)
    int* csr_src              = (int*)alloc((size_t)E * 4);
    unsigned short* csr_eah   = (unsigned short*)alloc((size_t)E * 16 * 2);  // bf16
    bool pre = ((size_t)(w - (char*)d_ws) <= ws_size);

    // one memset over deg..cursor (adjacent)
    hipMemsetAsync(deg, 0, (size_t)((char*)cursor - (char*)deg) + (size_t)N * 4, stream);

    // CSR build
    count_k<<<(E + 255) / 256, 256, 0, stream>>>(dst, E, deg);
    int nChunks = (N + 1023) / 1024;
    scan_chunk<<<nChunks, 1024, 0, stream>>>(deg, row_start, chunkSums, N);
    scan_sums<<<1, 128, 0, stream>>>(chunkSums, nChunks);
    scan_add<<<(N + 255) / 256, 256, 0, stream>>>(row_start, chunkSums, N, E);
    fill_k<<<(E + 255) / 256, 256, 0, stream>>>(dst, E, row_start, cursor, csr);
    // determinism: fix within-row order (atomic fill order is race-dependent)
    sort_rows_k<<<(N + 255) / 256, 256, 0, stream>>>(row_start, csr, N);

    // one-time edge-data permutation into CSR order (bf16 output)
    if (pre) {
        gather_edges<<<((size_t)E * 4 + 255) / 256, 256, 0, stream>>>(
            csr, src, (const float4*)eattr, csr_src, csr_eah, E);
    }

    // 3 transformer layers
    const float* Hin = x;
    for (int l = 0; l < 3; ++l) {
        gemm_qkvs<<<2048, 128, 0, stream>>>(Hin,
            Wq + l * 4096, bq + l * 64, Wk + l * 4096, bk + l * 64,
            Wv + l * 4096, bv + l * 64, Wskip + l * 4096, bskip + l * 64,
            Q, KVh, S, N);
        if (pre) {
            attn_pre<<<4096, 256, 0, stream>>>(Q, (const unsigned int*)KVh, S,
                row_start, csr_src, csr_eah,
                We + l * 1024, be + l * 64, H, N, (l < 2) ? 1 : 0);
        } else {
            attn_k<<<4096, 256, 0, stream>>>(Q, (const unsigned int*)KVh, S,
                row_start, csr, src, eattr,
                We + l * 1024, be + l * 64, H, N, (l < 2) ? 1 : 0);
        }
        Hin = H;
    }

    // deterministic pool + head
    pool_mean_k<<<128, 256, 0, stream>>>(Hin, batch, pooled, N);
    mlp_k<<<128, 64, 0, stream>>>(pooled, lin1_w, lin1_b, lin2_w, lin2_b,
                                  (float*)d_out);
}